// Round 9
// baseline (386.820 us; speedup 1.0000x reference)
//
#include <hip/hip_runtime.h>

#define B 64
#define N 2048
#define E 32768
#define D 256
#define H 256
#define GCH 16         // gather blocks per batch (128 rows per block)
#define SEG 8          // edge segments per batch
#define EPB (E / SEG)  // 4096 edges per block

// ---------------------------------------------------------------------------
// Edge pass 1: w_part[b,seg,n] = sum_{e in seg: row<L, col==n} val[e]
//              sw_part[b,seg]  = sum_{e in seg: row<L} val[e]
// Also zeroes the per-batch gather-completion counters (block seg==0).
// ---------------------------------------------------------------------------
__global__ __launch_bounds__(512) void edge_w_kernel(
    const int* __restrict__ adj_row, const int* __restrict__ adj_col,
    const float* __restrict__ adj_val, const int* __restrict__ cur_len,
    float* __restrict__ w_part, float* __restrict__ sw_part,
    int* __restrict__ cnt)
{
    __shared__ float wloc[N];
    __shared__ float sred[8];
    const int b = blockIdx.x, seg = blockIdx.y, tid = threadIdx.x;
    const int L = *cur_len;

    if (seg == 0 && tid == 0) cnt[b] = 0;   // visible to gather: 2 dispatch
                                            // boundaries downstream
    ((float4*)wloc)[tid] = make_float4(0.f, 0.f, 0.f, 0.f);
    __syncthreads();

    const int base = b * E + seg * EPB;
    float svp = 0.f;
    #pragma unroll
    for (int k = 0; k < EPB / 512; ++k) {
        const int e = base + tid + k * 512;
        const int r = adj_row[e];
        if (r < L) {
            const float v = adj_val[e];
            atomicAdd(&wloc[adj_col[e]], v);
            svp += v;
        }
    }
    __syncthreads();

    float4* dst = (float4*)(w_part + ((size_t)b * SEG + seg) * N);
    dst[tid] = ((const float4*)wloc)[tid];

    for (int off = 32; off; off >>= 1) svp += __shfl_down(svp, off, 64);
    if ((tid & 63) == 0) sred[tid >> 6] = svp;
    __syncthreads();
    if (tid == 0) {
        float s = 0.f;
        #pragma unroll
        for (int i = 0; i < 8; ++i) s += sred[i];
        sw_part[b * SEG + seg] = s;
    }
}

// ---------------------------------------------------------------------------
// Edge pass 2: rebuild full w[b,:] in LDS from the 8 partials (float4,
// coalesced), then z_part[b,seg,m] = sum_{e in seg: col==m} w[row[e]]*val[e].
// ---------------------------------------------------------------------------
__global__ __launch_bounds__(512) void edge_z_kernel(
    const int* __restrict__ adj_row, const int* __restrict__ adj_col,
    const float* __restrict__ adj_val, const float* __restrict__ w_part,
    float* __restrict__ z_part)
{
    __shared__ float wfull[N];
    __shared__ float zloc[N];
    const int b = blockIdx.x, seg = blockIdx.y, tid = threadIdx.x;

    const float4* wp4 = (const float4*)(w_part + (size_t)b * SEG * N);
    float4 s = make_float4(0.f, 0.f, 0.f, 0.f);
    #pragma unroll
    for (int sg = 0; sg < SEG; ++sg) {
        const float4 v = wp4[sg * (N / 4) + tid];
        s.x += v.x; s.y += v.y; s.z += v.z; s.w += v.w;
    }
    ((float4*)wfull)[tid] = s;
    ((float4*)zloc)[tid]  = make_float4(0.f, 0.f, 0.f, 0.f);
    __syncthreads();

    const int base = b * E + seg * EPB;
    #pragma unroll
    for (int k = 0; k < EPB / 512; ++k) {
        const int e = base + tid + k * 512;
        const float wv = wfull[adj_row[e]];
        if (wv != 0.f) atomicAdd(&zloc[adj_col[e]], wv * adj_val[e]);
    }
    __syncthreads();

    float4* dst = (float4*)(z_part + ((size_t)b * SEG + seg) * N);
    dst[tid] = ((const float4*)zloc)[tid];
}

// ---------------------------------------------------------------------------
// Gather + fused head: u_part[b,g,:] = sum_{128-row group} z*emb-row, then
// the LAST gather block of batch b (per-batch atomic counter) computes the
// whole head for that batch inline:
//   u = sum_g u_part ; y = u@W1 + sw*b1 ; p = y@W2/L + b2 ;
//   out = relu(p@fc1_w + fc1_b)
// ---------------------------------------------------------------------------
__global__ __launch_bounds__(256) void gather_head_kernel(
    const int* __restrict__ neighbors, const float* __restrict__ emb,
    const float* __restrict__ z_part, float* __restrict__ u_part,
    int* __restrict__ cnt, const float* __restrict__ sw_part,
    const float* __restrict__ W1, const float* __restrict__ b1,
    const float* __restrict__ W2, const float* __restrict__ b2,
    const float* __restrict__ fc1_w, const float* __restrict__ fc1_b,
    const int* __restrict__ cur_len, float* __restrict__ out)
{
    const int b = blockIdx.x, grp = blockIdx.y, tid = threadIdx.x;
    const int lane = tid & 63, rg = tid >> 6;
    const int n0 = grp * 128;                 // 128 rows per block

    __shared__ float zh[2][128];
    __shared__ int   ns[128];
    {
        const int j = tid & 127, half = tid >> 7;
        float s = 0.f;
        #pragma unroll
        for (int sg = 0; sg < SEG / 2; ++sg)
            s += z_part[((size_t)b * SEG + half * (SEG / 2) + sg) * N + n0 + j];
        zh[half][j] = s;
        if (half == 0) ns[j] = neighbors[(size_t)b * N + n0 + j];
    }
    __syncthreads();

    const float4* __restrict__ emb4 = (const float4*)emb;
    float4 a0 = make_float4(0.f,0.f,0.f,0.f), a1 = a0, a2 = a0, a3 = a0;

    #pragma unroll 8
    for (int i = 0; i < 32; ++i) {            // 32 rows per wave
        const int j = i * 4 + rg;
        const float zv = zh[0][j] + zh[1][j];
        const size_t idx = (size_t)ns[j];
        const float4 v = emb4[idx * (D / 4) + lane];
        if ((i & 3) == 0)      { a0.x += zv*v.x; a0.y += zv*v.y; a0.z += zv*v.z; a0.w += zv*v.w; }
        else if ((i & 3) == 1) { a1.x += zv*v.x; a1.y += zv*v.y; a1.z += zv*v.z; a1.w += zv*v.w; }
        else if ((i & 3) == 2) { a2.x += zv*v.x; a2.y += zv*v.y; a2.z += zv*v.z; a2.w += zv*v.w; }
        else                   { a3.x += zv*v.x; a3.y += zv*v.y; a3.z += zv*v.z; a3.w += zv*v.w; }
    }
    float4 acc = make_float4(a0.x+a1.x+a2.x+a3.x, a0.y+a1.y+a2.y+a3.y,
                             a0.z+a1.z+a2.z+a3.z, a0.w+a1.w+a2.w+a3.w);

    __shared__ float4 red[256];
    red[tid] = acc;
    __syncthreads();
    if (tid < 64) {
        float4 a = red[tid], bb = red[tid + 64], c = red[tid + 128], d = red[tid + 192];
        float4 s = make_float4(a.x + bb.x + c.x + d.x, a.y + bb.y + c.y + d.y,
                               a.z + bb.z + c.z + d.z, a.w + bb.w + c.w + d.w);
        ((float4*)u_part)[((size_t)b * GCH + grp) * (D / 4) + tid] = s;
    }
    __syncthreads();

    // ---- last-block-done: release our stores, bump the batch counter ------
    __shared__ int is_last;
    __threadfence();                           // release u_part to device scope
    if (tid == 0) is_last = (atomicAdd(&cnt[b], 1) == GCH - 1) ? 1 : 0;
    __syncthreads();
    if (!is_last) return;
    __threadfence();                           // acquire other blocks' u_part

    // ---- inline head for batch b (256 threads, t = output column) ---------
    __shared__ float su[D];
    __shared__ float sy[H];
    __shared__ float sp[H];
    const int t = tid;

    float uacc = 0.f;
    #pragma unroll
    for (int g = 0; g < GCH; ++g)
        uacc += u_part[((size_t)b * GCH + g) * D + t];
    su[t] = uacc;
    __syncthreads();

    float sw = 0.f;
    #pragma unroll
    for (int i = 0; i < SEG; ++i) sw += sw_part[b * SEG + i];

    float v1 = sw * b1[t];
    #pragma unroll 8
    for (int d = 0; d < D; ++d) v1 += su[d] * W1[d * H + t];
    sy[t] = v1;
    __syncthreads();

    const float invL = 1.f / (float)(*cur_len);
    float v2 = 0.f;
    #pragma unroll 8
    for (int k = 0; k < H; ++k) v2 += sy[k] * W2[k * H + t];
    sp[t] = v2 * invL + b2[t];
    __syncthreads();

    float v3 = fc1_b[t];
    #pragma unroll 8
    for (int k = 0; k < H; ++k) v3 += sp[k] * fc1_w[k * H + t];
    out[(size_t)b * H + t] = fmaxf(v3, 0.f);
}

extern "C" void kernel_launch(void* const* d_in, const int* in_sizes, int n_in,
                              void* d_out, int out_size, void* d_ws, size_t ws_size,
                              hipStream_t stream) {
    const int*   neighbors = (const int*)  d_in[0];
    const int*   adj_row   = (const int*)  d_in[1];
    const int*   adj_col   = (const int*)  d_in[2];
    const float* adj_val   = (const float*)d_in[3];
    const float* emb_table = (const float*)d_in[4];
    const float* W1        = (const float*)d_in[5];
    const float* b1        = (const float*)d_in[6];
    const float* W2        = (const float*)d_in[7];
    const float* b2        = (const float*)d_in[8];
    const float* fc1_w     = (const float*)d_in[9];
    const float* fc1_b     = (const float*)d_in[10];
    const int*   cur_len   = (const int*)  d_in[11];
    float*       out       = (float*)d_out;

    // workspace layout (floats), all fully overwritten every call (no memset;
    // cnt is zeroed by edge_w two dispatch boundaries before gather uses it):
    // [w_part: B*SEG*N][z_part: B*SEG*N][sw_part: B*SEG][cnt: B][pad][u_part]
    float* wp_ws = (float*)d_ws;
    float* zp_ws = wp_ws + (size_t)B * SEG * N;
    float* sw_ws = zp_ws + (size_t)B * SEG * N;
    int*   cnt   = (int*)(sw_ws + (size_t)B * SEG);
    float* u_ws  = (float*)(cnt + B) + 60;      // keep 16B alignment

    edge_w_kernel<<<dim3(B, SEG), 512, 0, stream>>>(adj_row, adj_col, adj_val,
                                                    cur_len, wp_ws, sw_ws, cnt);
    edge_z_kernel<<<dim3(B, SEG), 512, 0, stream>>>(adj_row, adj_col, adj_val,
                                                    wp_ws, zp_ws);
    gather_head_kernel<<<dim3(B, GCH), 256, 0, stream>>>(
        neighbors, emb_table, zp_ws, u_ws, cnt, sw_ws,
        W1, b1, W2, b2, fc1_w, fc1_b, cur_len, out);
}

// Round 10
// 251.552 us; speedup vs baseline: 1.5377x; 1.5377x over previous
//
#include <hip/hip_runtime.h>

#define B 64
#define N 2048
#define E 32768
#define D 256
#define H 256
#define GCH 16         // gather blocks per batch (128 rows per block)
#define SEG 8          // edge segments per batch
#define EPB (E / SEG)  // 4096 edges per block

// ---------------------------------------------------------------------------
// Edge pass 1: w_part[b,seg,n] = sum_{e in seg: row<L, col==n} val[e]
//              sw_part[b,seg]  = sum_{e in seg: row<L} val[e]
// int4/float4 vectorized edge streaming; LDS histogram; float4 flush.
// Block (b, seg==0) zeroes the per-batch completion counters (consumed two
// dispatch boundaries later by gather_head).
// ---------------------------------------------------------------------------
__global__ __launch_bounds__(512) void edge_w_kernel(
    const int* __restrict__ adj_row, const int* __restrict__ adj_col,
    const float* __restrict__ adj_val, const int* __restrict__ cur_len,
    float* __restrict__ w_part, float* __restrict__ sw_part,
    int* __restrict__ cnt)
{
    __shared__ float wloc[N];
    __shared__ float sred[8];
    const int b = blockIdx.x, seg = blockIdx.y, tid = threadIdx.x;
    const int L = *cur_len;

    if (seg == 0 && tid == 0) cnt[b] = 0;
    ((float4*)wloc)[tid] = make_float4(0.f, 0.f, 0.f, 0.f);
    __syncthreads();

    const int base = b * E + seg * EPB;            // multiple of 4096 -> aligned
    const int4*   row4 = (const int4*)  (adj_row + base);
    const int4*   col4 = (const int4*)  (adj_col + base);
    const float4* val4 = (const float4*)(adj_val + base);

    float svp = 0.f;
    #pragma unroll
    for (int k = 0; k < EPB / (512 * 4); ++k) {    // 2 iterations
        const int    i = tid + k * 512;
        const int4   r = row4[i];
        const int4   c = col4[i];
        const float4 v = val4[i];
        if (r.x < L) { atomicAdd(&wloc[c.x], v.x); svp += v.x; }
        if (r.y < L) { atomicAdd(&wloc[c.y], v.y); svp += v.y; }
        if (r.z < L) { atomicAdd(&wloc[c.z], v.z); svp += v.z; }
        if (r.w < L) { atomicAdd(&wloc[c.w], v.w); svp += v.w; }
    }
    __syncthreads();

    float4* dst = (float4*)(w_part + ((size_t)b * SEG + seg) * N);
    dst[tid] = ((const float4*)wloc)[tid];

    for (int off = 32; off; off >>= 1) svp += __shfl_down(svp, off, 64);
    if ((tid & 63) == 0) sred[tid >> 6] = svp;
    __syncthreads();
    if (tid == 0) {
        float s = 0.f;
        #pragma unroll
        for (int i = 0; i < 8; ++i) s += sred[i];
        sw_part[b * SEG + seg] = s;
    }
}

// ---------------------------------------------------------------------------
// Edge pass 2: rebuild full w[b,:] in LDS from the 8 partials (float4),
// then z_part[b,seg,m] = sum_{e in seg: col==m} w[row[e]] * val[e].
// Edge slice is the same one this blockIdx read in pass 1 (likely L2-warm).
// ---------------------------------------------------------------------------
__global__ __launch_bounds__(512) void edge_z_kernel(
    const int* __restrict__ adj_row, const int* __restrict__ adj_col,
    const float* __restrict__ adj_val, const float* __restrict__ w_part,
    float* __restrict__ z_part)
{
    __shared__ float wfull[N];
    __shared__ float zloc[N];
    const int b = blockIdx.x, seg = blockIdx.y, tid = threadIdx.x;

    const float4* wp4 = (const float4*)(w_part + (size_t)b * SEG * N);
    float4 s = make_float4(0.f, 0.f, 0.f, 0.f);
    #pragma unroll
    for (int sg = 0; sg < SEG; ++sg) {
        const float4 v = wp4[sg * (N / 4) + tid];
        s.x += v.x; s.y += v.y; s.z += v.z; s.w += v.w;
    }
    ((float4*)wfull)[tid] = s;
    ((float4*)zloc)[tid]  = make_float4(0.f, 0.f, 0.f, 0.f);
    __syncthreads();

    const int base = b * E + seg * EPB;
    const int4*   row4 = (const int4*)  (adj_row + base);
    const int4*   col4 = (const int4*)  (adj_col + base);
    const float4* val4 = (const float4*)(adj_val + base);

    #pragma unroll
    for (int k = 0; k < EPB / (512 * 4); ++k) {    // 2 iterations
        const int    i = tid + k * 512;
        const int4   r = row4[i];
        const int4   c = col4[i];
        const float4 v = val4[i];
        float wv;
        wv = wfull[r.x]; if (wv != 0.f) atomicAdd(&zloc[c.x], wv * v.x);
        wv = wfull[r.y]; if (wv != 0.f) atomicAdd(&zloc[c.y], wv * v.y);
        wv = wfull[r.z]; if (wv != 0.f) atomicAdd(&zloc[c.z], wv * v.z);
        wv = wfull[r.w]; if (wv != 0.f) atomicAdd(&zloc[c.w], wv * v.w);
    }
    __syncthreads();

    float4* dst = (float4*)(z_part + ((size_t)b * SEG + seg) * N);
    dst[tid] = ((const float4*)zloc)[tid];
}

// ---------------------------------------------------------------------------
// Gather + fused head (fence-free last-block-done):
//   u_part[b,g,:] written with AGENT-scope relaxed atomic stores (sc-coherent,
//   no L2 flush). __syncthreads() drains each wave's stores to the device
//   coherent point; then one relaxed agent-scope atomicAdd on cnt[b]. The
//   block seeing old==GCH-1 reads u_part back with agent-scope loads and
//   computes the head for batch b inline.
// ---------------------------------------------------------------------------
__global__ __launch_bounds__(256) void gather_head_kernel(
    const int* __restrict__ neighbors, const float* __restrict__ emb,
    const float* __restrict__ z_part, float* __restrict__ u_part,
    int* __restrict__ cnt, const float* __restrict__ sw_part,
    const float* __restrict__ W1, const float* __restrict__ b1,
    const float* __restrict__ W2, const float* __restrict__ b2,
    const float* __restrict__ fc1_w, const float* __restrict__ fc1_b,
    const int* __restrict__ cur_len, float* __restrict__ out)
{
    const int b = blockIdx.x, grp = blockIdx.y, tid = threadIdx.x;
    const int lane = tid & 63, rg = tid >> 6;
    const int n0 = grp * 128;                 // 128 rows per block

    __shared__ float zh[2][128];
    __shared__ int   ns[128];
    {
        const int j = tid & 127, half = tid >> 7;
        float s = 0.f;
        #pragma unroll
        for (int sg = 0; sg < SEG / 2; ++sg)
            s += z_part[((size_t)b * SEG + half * (SEG / 2) + sg) * N + n0 + j];
        zh[half][j] = s;
        if (half == 0) ns[j] = neighbors[(size_t)b * N + n0 + j];
    }
    __syncthreads();

    const float4* __restrict__ emb4 = (const float4*)emb;
    float4 a0 = make_float4(0.f,0.f,0.f,0.f), a1 = a0, a2 = a0, a3 = a0;

    #pragma unroll 8
    for (int i = 0; i < 32; ++i) {            // 32 rows per wave
        const int j = i * 4 + rg;
        const float zv = zh[0][j] + zh[1][j];
        const size_t idx = (size_t)ns[j];
        const float4 v = emb4[idx * (D / 4) + lane];
        if ((i & 3) == 0)      { a0.x += zv*v.x; a0.y += zv*v.y; a0.z += zv*v.z; a0.w += zv*v.w; }
        else if ((i & 3) == 1) { a1.x += zv*v.x; a1.y += zv*v.y; a1.z += zv*v.z; a1.w += zv*v.w; }
        else if ((i & 3) == 2) { a2.x += zv*v.x; a2.y += zv*v.y; a2.z += zv*v.z; a2.w += zv*v.w; }
        else                   { a3.x += zv*v.x; a3.y += zv*v.y; a3.z += zv*v.z; a3.w += zv*v.w; }
    }
    float4 acc = make_float4(a0.x+a1.x+a2.x+a3.x, a0.y+a1.y+a2.y+a3.y,
                             a0.z+a1.z+a2.z+a3.z, a0.w+a1.w+a2.w+a3.w);

    __shared__ float4 red[256];
    red[tid] = acc;
    __syncthreads();
    if (tid < 64) {
        float4 a = red[tid], bb = red[tid + 64], c = red[tid + 128], d = red[tid + 192];
        float* dst = u_part + ((size_t)b * GCH + grp) * D + tid * 4;
        __hip_atomic_store(dst + 0, a.x + bb.x + c.x + d.x,
                           __ATOMIC_RELAXED, __HIP_MEMORY_SCOPE_AGENT);
        __hip_atomic_store(dst + 1, a.y + bb.y + c.y + d.y,
                           __ATOMIC_RELAXED, __HIP_MEMORY_SCOPE_AGENT);
        __hip_atomic_store(dst + 2, a.z + bb.z + c.z + d.z,
                           __ATOMIC_RELAXED, __HIP_MEMORY_SCOPE_AGENT);
        __hip_atomic_store(dst + 3, a.w + bb.w + c.w + d.w,
                           __ATOMIC_RELAXED, __HIP_MEMORY_SCOPE_AGENT);
    }
    __syncthreads();   // drains every wave's outstanding stores (vmcnt) first

    __shared__ int is_last;
    if (tid == 0) {
        const int old = __hip_atomic_fetch_add(&cnt[b], 1, __ATOMIC_RELAXED,
                                               __HIP_MEMORY_SCOPE_AGENT);
        is_last = (old == GCH - 1) ? 1 : 0;
    }
    __syncthreads();
    if (!is_last) return;

    // ---- inline head for batch b (256 threads, t = output column) ---------
    __shared__ float su[D];
    __shared__ float sy[H];
    __shared__ float sp[H];
    const int t = tid;

    float uacc = 0.f;
    #pragma unroll
    for (int g = 0; g < GCH; ++g)
        uacc += __hip_atomic_load(u_part + ((size_t)b * GCH + g) * D + t,
                                  __ATOMIC_RELAXED, __HIP_MEMORY_SCOPE_AGENT);
    su[t] = uacc;
    __syncthreads();

    float sw = 0.f;
    #pragma unroll
    for (int i = 0; i < SEG; ++i) sw += sw_part[b * SEG + i];

    float v1 = sw * b1[t];
    #pragma unroll 8
    for (int d = 0; d < D; ++d) v1 += su[d] * W1[d * H + t];
    sy[t] = v1;
    __syncthreads();

    const float invL = 1.f / (float)(*cur_len);
    float v2 = 0.f;
    #pragma unroll 8
    for (int k = 0; k < H; ++k) v2 += sy[k] * W2[k * H + t];
    sp[t] = v2 * invL + b2[t];
    __syncthreads();

    float v3 = fc1_b[t];
    #pragma unroll 8
    for (int k = 0; k < H; ++k) v3 += sp[k] * fc1_w[k * H + t];
    out[(size_t)b * H + t] = fmaxf(v3, 0.f);
}

extern "C" void kernel_launch(void* const* d_in, const int* in_sizes, int n_in,
                              void* d_out, int out_size, void* d_ws, size_t ws_size,
                              hipStream_t stream) {
    const int*   neighbors = (const int*)  d_in[0];
    const int*   adj_row   = (const int*)  d_in[1];
    const int*   adj_col   = (const int*)  d_in[2];
    const float* adj_val   = (const float*)d_in[3];
    const float* emb_table = (const float*)d_in[4];
    const float* W1        = (const float*)d_in[5];
    const float* b1        = (const float*)d_in[6];
    const float* W2        = (const float*)d_in[7];
    const float* b2        = (const float*)d_in[8];
    const float* fc1_w     = (const float*)d_in[9];
    const float* fc1_b     = (const float*)d_in[10];
    const int*   cur_len   = (const int*)  d_in[11];
    float*       out       = (float*)d_out;

    // workspace layout (floats), all fully overwritten every call (no memset;
    // cnt is zeroed by edge_w two dispatch boundaries before gather uses it):
    // [w_part: B*SEG*N][z_part: B*SEG*N][sw_part: B*SEG][cnt: B][pad][u_part]
    float* wp_ws = (float*)d_ws;
    float* zp_ws = wp_ws + (size_t)B * SEG * N;
    float* sw_ws = zp_ws + (size_t)B * SEG * N;
    int*   cnt   = (int*)(sw_ws + (size_t)B * SEG);
    float* u_ws  = (float*)(cnt + B) + 60;      // keep 16B alignment

    edge_w_kernel<<<dim3(B, SEG), 512, 0, stream>>>(adj_row, adj_col, adj_val,
                                                    cur_len, wp_ws, sw_ws, cnt);
    edge_z_kernel<<<dim3(B, SEG), 512, 0, stream>>>(adj_row, adj_col, adj_val,
                                                    wp_ws, zp_ws);
    gather_head_kernel<<<dim3(B, GCH), 256, 0, stream>>>(
        neighbors, emb_table, zp_ws, u_ws, cnt, sw_ws,
        W1, b1, W2, b2, fc1_w, fc1_b, cur_len, out);
}

// Round 11
// 224.083 us; speedup vs baseline: 1.7262x; 1.1226x over previous
//
#include <hip/hip_runtime.h>

#define B 64
#define N 2048
#define E 32768
#define D 256
#define H 256
#define GCH 32         // gather blocks per batch (64 rows per block; 2048 blocks)
#define SEG 8          // edge segments per batch
#define EPB (E / SEG)  // 4096 edges per block

// ---------------------------------------------------------------------------
// Edge pass 1: w_part[b,seg,n] = sum_{e in seg: row<L, col==n} val[e]
//              sw_part[b,seg]  = sum_{e in seg: row<L} val[e]
// int4/float4 vectorized edge streaming; LDS histogram; float4 flush.
// ---------------------------------------------------------------------------
__global__ __launch_bounds__(512) void edge_w_kernel(
    const int* __restrict__ adj_row, const int* __restrict__ adj_col,
    const float* __restrict__ adj_val, const int* __restrict__ cur_len,
    float* __restrict__ w_part, float* __restrict__ sw_part)
{
    __shared__ float wloc[N];
    __shared__ float sred[8];
    const int b = blockIdx.x, seg = blockIdx.y, tid = threadIdx.x;
    const int L = *cur_len;

    ((float4*)wloc)[tid] = make_float4(0.f, 0.f, 0.f, 0.f);
    __syncthreads();

    const int base = b * E + seg * EPB;            // multiple of 4096 -> aligned
    const int4*   row4 = (const int4*)  (adj_row + base);
    const int4*   col4 = (const int4*)  (adj_col + base);
    const float4* val4 = (const float4*)(adj_val + base);

    float svp = 0.f;
    #pragma unroll
    for (int k = 0; k < EPB / (512 * 4); ++k) {    // 2 iterations
        const int    i = tid + k * 512;
        const int4   r = row4[i];
        const int4   c = col4[i];
        const float4 v = val4[i];
        if (r.x < L) { atomicAdd(&wloc[c.x], v.x); svp += v.x; }
        if (r.y < L) { atomicAdd(&wloc[c.y], v.y); svp += v.y; }
        if (r.z < L) { atomicAdd(&wloc[c.z], v.z); svp += v.z; }
        if (r.w < L) { atomicAdd(&wloc[c.w], v.w); svp += v.w; }
    }
    __syncthreads();

    float4* dst = (float4*)(w_part + ((size_t)b * SEG + seg) * N);
    dst[tid] = ((const float4*)wloc)[tid];

    for (int off = 32; off; off >>= 1) svp += __shfl_down(svp, off, 64);
    if ((tid & 63) == 0) sred[tid >> 6] = svp;
    __syncthreads();
    if (tid == 0) {
        float s = 0.f;
        #pragma unroll
        for (int i = 0; i < 8; ++i) s += sred[i];
        sw_part[b * SEG + seg] = s;
    }
}

// ---------------------------------------------------------------------------
// Edge pass 2: rebuild full w[b,:] in LDS from the 8 partials (float4),
// then z_part[b,seg,m] = sum_{e in seg: col==m} w[row[e]] * val[e].
// ---------------------------------------------------------------------------
__global__ __launch_bounds__(512) void edge_z_kernel(
    const int* __restrict__ adj_row, const int* __restrict__ adj_col,
    const float* __restrict__ adj_val, const float* __restrict__ w_part,
    float* __restrict__ z_part)
{
    __shared__ float wfull[N];
    __shared__ float zloc[N];
    const int b = blockIdx.x, seg = blockIdx.y, tid = threadIdx.x;

    const float4* wp4 = (const float4*)(w_part + (size_t)b * SEG * N);
    float4 s = make_float4(0.f, 0.f, 0.f, 0.f);
    #pragma unroll
    for (int sg = 0; sg < SEG; ++sg) {
        const float4 v = wp4[sg * (N / 4) + tid];
        s.x += v.x; s.y += v.y; s.z += v.z; s.w += v.w;
    }
    ((float4*)wfull)[tid] = s;
    ((float4*)zloc)[tid]  = make_float4(0.f, 0.f, 0.f, 0.f);
    __syncthreads();

    const int base = b * E + seg * EPB;
    const int4*   row4 = (const int4*)  (adj_row + base);
    const int4*   col4 = (const int4*)  (adj_col + base);
    const float4* val4 = (const float4*)(adj_val + base);

    #pragma unroll
    for (int k = 0; k < EPB / (512 * 4); ++k) {    // 2 iterations
        const int    i = tid + k * 512;
        const int4   r = row4[i];
        const int4   c = col4[i];
        const float4 v = val4[i];
        float wv;
        wv = wfull[r.x]; if (wv != 0.f) atomicAdd(&zloc[c.x], wv * v.x);
        wv = wfull[r.y]; if (wv != 0.f) atomicAdd(&zloc[c.y], wv * v.y);
        wv = wfull[r.z]; if (wv != 0.f) atomicAdd(&zloc[c.z], wv * v.z);
        wv = wfull[r.w]; if (wv != 0.f) atomicAdd(&zloc[c.w], wv * v.w);
    }
    __syncthreads();

    float4* dst = (float4*)(z_part + ((size_t)b * SEG + seg) * N);
    dst[tid] = ((const float4*)zloc)[tid];
}

// ---------------------------------------------------------------------------
// Gather: u_part[b,g,:] = sum_{n in 64-row group g} z[b,n]*emb[neighbors[b,n],:]
// Grid (B, 32) = 2048 blocks -> 8 blocks/CU (full 32-wave occupancy; the
// loop is latency-bound per R10's counters, so wave count is the lever).
// One wave per row: lane = float4 offset -> coalesced 1KB row reads.
// ---------------------------------------------------------------------------
__global__ __launch_bounds__(256) void gather_kernel(
    const int* __restrict__ neighbors, const float* __restrict__ emb,
    const float* __restrict__ z_part, float* __restrict__ u_part)
{
    const int b = blockIdx.x, grp = blockIdx.y, tid = threadIdx.x;
    const int lane = tid & 63, rg = tid >> 6;
    const int n0 = grp * 64;                  // 64 rows per block

    __shared__ float zh[2][64];
    __shared__ int   ns[64];
    if (tid < 128) {
        const int j = tid & 63, half = tid >> 6;
        float s = 0.f;
        #pragma unroll
        for (int sg = 0; sg < SEG / 2; ++sg)
            s += z_part[((size_t)b * SEG + half * (SEG / 2) + sg) * N + n0 + j];
        zh[half][j] = s;
        if (half == 0) ns[j] = neighbors[(size_t)b * N + n0 + j];
    }
    __syncthreads();

    const float4* __restrict__ emb4 = (const float4*)emb;
    float4 a0 = make_float4(0.f,0.f,0.f,0.f), a1 = a0, a2 = a0, a3 = a0;

    #pragma unroll
    for (int i = 0; i < 16; ++i) {            // 16 rows per wave
        const int j = i * 4 + rg;
        const float zv = zh[0][j] + zh[1][j];
        const size_t idx = (size_t)ns[j];
        const float4 v = emb4[idx * (D / 4) + lane];
        if ((i & 3) == 0)      { a0.x += zv*v.x; a0.y += zv*v.y; a0.z += zv*v.z; a0.w += zv*v.w; }
        else if ((i & 3) == 1) { a1.x += zv*v.x; a1.y += zv*v.y; a1.z += zv*v.z; a1.w += zv*v.w; }
        else if ((i & 3) == 2) { a2.x += zv*v.x; a2.y += zv*v.y; a2.z += zv*v.z; a2.w += zv*v.w; }
        else                   { a3.x += zv*v.x; a3.y += zv*v.y; a3.z += zv*v.z; a3.w += zv*v.w; }
    }
    float4 acc = make_float4(a0.x+a1.x+a2.x+a3.x, a0.y+a1.y+a2.y+a3.y,
                             a0.z+a1.z+a2.z+a3.z, a0.w+a1.w+a2.w+a3.w);

    __shared__ float4 red[256];
    red[tid] = acc;
    __syncthreads();
    if (tid < 64) {
        float4 a = red[tid], bb = red[tid + 64], c = red[tid + 128], d = red[tid + 192];
        float4 s = make_float4(a.x + bb.x + c.x + d.x, a.y + bb.y + c.y + d.y,
                               a.z + bb.z + c.z + d.z, a.w + bb.w + c.w + d.w);
        ((float4*)u_part)[((size_t)b * GCH + grp) * (D / 4) + tid] = s;
    }
}

// ---------------------------------------------------------------------------
// Head: u = sum_g u_part ; y = u@W1 + sw*b1 ; p = y@W2/L + b2 ;
//       out = relu(p@fc1_w + fc1_b).
// 1024 threads: t = output col, s = 4-way k-split. sw from 8 partials inline.
// ---------------------------------------------------------------------------
__global__ __launch_bounds__(1024) void head_kernel(
    const float* __restrict__ u_part, const float* __restrict__ sw_part,
    const float* __restrict__ W1, const float* __restrict__ b1,
    const float* __restrict__ W2, const float* __restrict__ b2,
    const float* __restrict__ fc1_w, const float* __restrict__ fc1_b,
    const int* __restrict__ cur_len, float* __restrict__ out)
{
    const int b = blockIdx.x;
    const int t = threadIdx.x & 255;   // output column
    const int s = threadIdx.x >> 8;    // k-split group (0..3)
    __shared__ float red[4][256];
    __shared__ float su[D];
    __shared__ float sy[H];
    __shared__ float sp[H];

    float part = 0.f;
    #pragma unroll
    for (int c = 0; c < GCH / 4; ++c)
        part += u_part[((size_t)b * GCH + s * (GCH / 4) + c) * D + t];
    red[s][t] = part;
    __syncthreads();
    if (s == 0) su[t] = red[0][t] + red[1][t] + red[2][t] + red[3][t];
    __syncthreads();

    part = 0.f;
    #pragma unroll 8
    for (int k = 0; k < 64; ++k) {
        const int d = s * 64 + k;
        part += su[d] * W1[d * H + t];
    }
    red[s][t] = part;
    __syncthreads();
    if (s == 0) {
        float sw = 0.f;
        #pragma unroll
        for (int i = 0; i < SEG; ++i) sw += sw_part[b * SEG + i];
        sy[t] = red[0][t] + red[1][t] + red[2][t] + red[3][t] + sw * b1[t];
    }
    __syncthreads();

    const float invL = 1.f / (float)(*cur_len);
    part = 0.f;
    #pragma unroll 8
    for (int k = 0; k < 64; ++k) {
        const int d = s * 64 + k;
        part += sy[d] * W2[d * H + t];
    }
    red[s][t] = part;
    __syncthreads();
    if (s == 0)
        sp[t] = (red[0][t] + red[1][t] + red[2][t] + red[3][t]) * invL + b2[t];
    __syncthreads();

    part = 0.f;
    #pragma unroll 8
    for (int k = 0; k < 64; ++k) {
        const int d = s * 64 + k;
        part += sp[d] * fc1_w[d * H + t];
    }
    red[s][t] = part;
    __syncthreads();
    if (s == 0) {
        const float v = red[0][t] + red[1][t] + red[2][t] + red[3][t] + fc1_b[t];
        out[(size_t)b * H + t] = fmaxf(v, 0.f);
    }
}

extern "C" void kernel_launch(void* const* d_in, const int* in_sizes, int n_in,
                              void* d_out, int out_size, void* d_ws, size_t ws_size,
                              hipStream_t stream) {
    const int*   neighbors = (const int*)  d_in[0];
    const int*   adj_row   = (const int*)  d_in[1];
    const int*   adj_col   = (const int*)  d_in[2];
    const float* adj_val   = (const float*)d_in[3];
    const float* emb_table = (const float*)d_in[4];
    const float* W1        = (const float*)d_in[5];
    const float* b1        = (const float*)d_in[6];
    const float* W2        = (const float*)d_in[7];
    const float* b2        = (const float*)d_in[8];
    const float* fc1_w     = (const float*)d_in[9];
    const float* fc1_b     = (const float*)d_in[10];
    const int*   cur_len   = (const int*)  d_in[11];
    float*       out       = (float*)d_out;

    // workspace layout (floats), all fully overwritten every call (no memset):
    // [w_part: B*SEG*N][z_part: B*SEG*N][sw_part: B*SEG][u_part: B*GCH*D]
    float* wp_ws = (float*)d_ws;
    float* zp_ws = wp_ws + (size_t)B * SEG * N;
    float* sw_ws = zp_ws + (size_t)B * SEG * N;
    float* u_ws  = sw_ws + (size_t)B * SEG;     // 16B-aligned (B*SEG=512)

    edge_w_kernel<<<dim3(B, SEG), 512, 0, stream>>>(adj_row, adj_col, adj_val,
                                                    cur_len, wp_ws, sw_ws);
    edge_z_kernel<<<dim3(B, SEG), 512, 0, stream>>>(adj_row, adj_col, adj_val,
                                                    wp_ws, zp_ws);
    gather_kernel<<<dim3(B, GCH), 256, 0, stream>>>(neighbors, emb_table, zp_ws, u_ws);
    head_kernel<<<B, 1024, 0, stream>>>(u_ws, sw_ws, W1, b1, W2, b2,
                                        fc1_w, fc1_b, cur_len, out);
}